// Round 14
// baseline (59.918 us; speedup 1.0000x reference)
//
#include <hip/hip_runtime.h>
#include <stdint.h>

typedef __bf16 bf16x8 __attribute__((ext_vector_type(8)));
typedef float  f32x4  __attribute__((ext_vector_type(4)));

#define HW   3136
#define WID  56
#define CIN  128
#define SQ   32
#define NPIX 100352      // 32*3136
#define PHW  3364        // 58*58 padded pixels per image

// workspace layout (bytes unless noted)
#define OFF_BSQ 0              // f32[32]  (float offset 0)
#define OFF_BE  32             // f32[256] (float offset 32) e1 then e3
#define WSQF_BYTES_OFF 1152    // bf16 [2mf*4kc][64 lane][8] = 8192 B
#define WE1F_BYTES_OFF 9344    // bf16 [8 mf][64 lane][8] = 8192 B
#define WE3F_BYTES_OFF 17536   // bf16 [8 mf][9 tap][64 lane][8] = 73728 B
#define HQ_BYTES_OFF   91264   // bf16 [32 img][58*58 px][32 ci] = 6,889,472 B

__device__ __forceinline__ float quant_w8(float x){
  float xc = fminf(fmaxf(x,-1.f),1.f);
  return fminf(rintf(xc*128.f)*0.0078125f, 0.9921875f);
}
// weight as integer n = 128*wq in [-128,127], stored as exact bf16
__device__ __forceinline__ ushort wq_int_bf16(float x){
  float xc = fminf(fmaxf(x,-1.f),1.f);
  float n = fminf(rintf(xc*128.f), 127.f);
  return (ushort)(__float_as_uint(n)>>16);
}
__device__ __forceinline__ uint pack2f(float a, float b){
  return (__float_as_uint(a)>>16) | (__float_as_uint(b)&0xffff0000u);
}

__global__ void prep_kernel(const float* __restrict__ wsq, const float* __restrict__ bsq,
                            const float* __restrict__ we1, const float* __restrict__ be1,
                            const float* __restrict__ we3, const float* __restrict__ be3,
                            float* __restrict__ ws){
  int tid = blockIdx.x*blockDim.x+threadIdx.x;
  int nth = gridDim.x*blockDim.x;
  ushort* wsqf = (ushort*)((char*)ws + WSQF_BYTES_OFF);
  ushort* we1f = (ushort*)((char*)ws + WE1F_BYTES_OFF);
  ushort* we3f = (ushort*)((char*)ws + WE3F_BYTES_OFF);
  for (int i=tid;i<SQ;i+=nth) ws[OFF_BSQ+i]=quant_w8(bsq[i]);
  for (int i=tid;i<256;i+=nth) ws[OFF_BE+i] = (i<128)? quant_w8(be1[i]) : quant_w8(be3[i-128]);
  // squeeze W frags: A[co=mf*16+(l&15)][ci=kc*32+(l>>4)*8+j], src wsq (32,128)
  for (int i=tid;i<4096;i+=nth){
    int mfkc=i>>9, l=(i>>3)&63, j=i&7;
    int mf=mfkc>>2, kc=mfkc&3;
    int co=mf*16+(l&15), ci=kc*32+(l>>4)*8+j;
    wsqf[i] = wq_int_bf16(wsq[co*CIN+ci]);
  }
  // e1 frags: [co=mf*16+(l&15)][k=ci=(l>>4)*8+j], src we1 (128,32)
  for (int i=tid;i<4096;i+=nth){
    int mf=i>>9, l=(i>>3)&63, j=i&7;
    int co=mf*16+(l&15), ci=(l>>4)*8+j;
    we1f[i] = wq_int_bf16(we1[co*SQ+ci]);
  }
  // e3 frags per tap, src we3 (128,32,3,3)
  for (int i=tid;i<36864;i+=nth){
    int mf=i/4608, r=i-mf*4608, t=r>>9, l=(r>>3)&63, j=r&7;
    int co=mf*16+(l&15), ci=(l>>4)*8+j;
    we3f[i] = wq_int_bf16(we3[(co*SQ+ci)*9+t]);
  }
}

// squeeze via MFMA, 1 pixel-block (16 px) per wave. Grid = NPIX/64 WGs of 4 waves.
// Writes h as bf16 m32 values into zero-padded [58][58] per-image buffer.
__global__ __launch_bounds__(256) void squeeze_kernel(const float* __restrict__ x,
    const float* __restrict__ ws, ushort* __restrict__ hq){
  int tid = threadIdx.x, wid = tid>>6, lane = tid&63;
  int colg = lane&15, kg = lane>>4;

  int pixbase = (blockIdx.x*4 + wid)*16;
  int n = pixbase/HW;
  int rem = pixbase - n*HW + colg;          // pixel index within image
  const float* xp = x + (size_t)n*CIN*HW + rem;

  float xv[32];
  #pragma unroll
  for (int kc=0;kc<4;++kc)
    #pragma unroll
    for (int j=0;j<8;++j)
      xv[kc*8+j] = xp[(size_t)(kc*32 + kg*8 + j)*HW];

  const bf16x8* wsqf = (const bf16x8*)((const char*)ws + WSQF_BYTES_OFF);
  bf16x8 W[8];
  #pragma unroll
  for (int q=0;q<8;++q) W[q] = wsqf[q*64 + lane];

  bf16x8 Bf[4];
  #pragma unroll
  for (int kc=0;kc<4;++kc){
    float m[8];
    #pragma unroll
    for (int j=0;j<8;++j){
      float v = fminf(fmaxf(xv[kc*8+j],-4.f),4.f);
      m[j] = fminf(rintf(v*32.f), 127.f);   // m = 32*xq, exact bf16
    }
    union { uint u[4]; bf16x8 v; } cv;
    #pragma unroll
    for (int q=0;q<4;++q) cv.u[q] = pack2f(m[q*2], m[q*2+1]);
    Bf[kc] = cv.v;
  }

  f32x4 acc0 = (f32x4){0.f,0.f,0.f,0.f};
  f32x4 acc1 = (f32x4){0.f,0.f,0.f,0.f};
  #pragma unroll
  for (int kc=0;kc<4;++kc){
    acc0 = __builtin_amdgcn_mfma_f32_16x16x32_bf16(W[kc],   Bf[kc], acc0, 0,0,0);
    acc1 = __builtin_amdgcn_mfma_f32_16x16x32_bf16(W[4+kc], Bf[kc], acc1, 0,0,0);
  }

  // epilogue: y = acc/4096 + b; q8@8; relu; qact13@4; q8@4 -> m32 bf16
  int row = rem/WID, col = rem - row*WID;
  size_t phq = (size_t)n*PHW + (row+1)*58 + (col+1);
  #pragma unroll
  for (int mf=0;mf<2;++mf){
    f32x4 a = mf ? acc1 : acc0;
    float bias[4], m[4];
    #pragma unroll
    for (int r=0;r<4;++r){
      bias[r] = ws[OFF_BSQ + mf*16 + kg*4 + r];
      float y = fmaf(a[r], 0.000244140625f, bias[r]);
      y = fminf(fmaxf(y,-8.f),8.f);
      y = fminf(rintf(y*16.f)*0.0625f, 7.9375f);
      y = fmaxf(y,0.f);
      y = fminf(y,4.f);
      y = fminf(y,0.9998779296875f);
      m[r] = rintf(y*32.f);                 // m32 in {0,2,...,32}, exact bf16
    }
    uint2 p;
    p.x = pack2f(m[0], m[1]);
    p.y = pack2f(m[2], m[3]);
    *(uint2*)(hq + phq*32 + mf*16 + kg*4) = p;
  }
}

// fused expand e1+e3, B-frags straight from padded global hq (no LDS, no barriers).
// One row-pair per WG. Grid (28, 32), 256 thr (4 waves). Verified r7 math/layout.
__global__ __launch_bounds__(256) void expand_kernel(const ushort* __restrict__ hq,
    const float* __restrict__ ws, float* __restrict__ out){
  int bry = blockIdx.x;            // 0..27 row-pair
  int n   = blockIdx.y;            // 0..31
  int tid = threadIdx.x, wid = tid>>6, lane = tid&63;
  int colg = lane&15, kg = lane>>4;

  int baseh[7];
  #pragma unroll
  for (int nf=0;nf<7;++nf){
    int p = bry*112 + nf*16 + colg;
    int rr = p/WID, c = p - rr*WID;
    baseh[nf] = (rr+1)*58 + c + 1;          // padded-image pixel index
  }

  f32x4 acc[4][7];
  #pragma unroll
  for (int mi=0;mi<4;++mi)
    #pragma unroll
    for (int nf=0;nf<7;++nf)
      acc[mi][nf] = (f32x4){0.f,0.f,0.f,0.f};

  const bf16x8* we1f = (const bf16x8*)((const char*)ws + WE1F_BYTES_OFF);
  const bf16x8* we3f = (const bf16x8*)((const char*)ws + WE3F_BYTES_OFF);
  const bf16x8* hb = (const bf16x8*)hq + (size_t)n*PHW*4 + kg;  // 4 x 16B per px

  #pragma unroll
  for (int t=0;t<9;++t){
    int off = (t/3 - 1)*58 + (t%3 - 1);
    bf16x8 B[7];
    #pragma unroll
    for (int nf=0;nf<7;++nf)
      B[nf] = hb[(size_t)(baseh[nf] + off)*4];
    bf16x8 A2 = we3f[(wid*9+t)*64 + lane];
    bf16x8 A3 = we3f[((wid+4)*9+t)*64 + lane];
    #pragma unroll
    for (int nf=0;nf<7;++nf){
      acc[2][nf] = __builtin_amdgcn_mfma_f32_16x16x32_bf16(B[nf], A2, acc[2][nf], 0,0,0);
      acc[3][nf] = __builtin_amdgcn_mfma_f32_16x16x32_bf16(B[nf], A3, acc[3][nf], 0,0,0);
    }
    if (t==4){
      bf16x8 A0 = we1f[wid*64 + lane];
      bf16x8 A1 = we1f[(wid+4)*64 + lane];
      #pragma unroll
      for (int nf=0;nf<7;++nf){
        acc[0][nf] = __builtin_amdgcn_mfma_f32_16x16x32_bf16(B[nf], A0, acc[0][nf], 0,0,0);
        acc[1][nf] = __builtin_amdgcn_mfma_f32_16x16x32_bf16(B[nf], A1, acc[1][nf], 0,0,0);
      }
    }
  }

  // epilogue: C col=cout(colg), row=pixel(kg*4+r) -> plain float4 stores (verified r7)
  #pragma unroll
  for (int mi=0;mi<4;++mi){
    int co = (wid+mi*4)*16 + colg;
    float bias = ws[OFF_BE + co];
    float* opb = out + (size_t)(n*256+co)*HW + bry*112 + kg*4;
    #pragma unroll
    for (int nf=0;nf<7;++nf){
      f32x4 a = acc[mi][nf];
      f32x4 yv;
      #pragma unroll
      for (int r=0;r<4;++r){
        float y = fmaf(a[r], 0.000244140625f, bias);
        y = fminf(fmaxf(y,-8.f),8.f);
        y = fminf(rintf(y*16.f)*0.0625f, 7.9375f);
        y = fmaxf(y,0.f);
        yv[r] = y;
      }
      *(f32x4*)(opb + nf*16) = yv;
    }
  }
}

extern "C" void kernel_launch(void* const* d_in, const int* in_sizes, int n_in,
                              void* d_out, int out_size, void* d_ws, size_t ws_size,
                              hipStream_t stream){
  const float* x   = (const float*)d_in[0];
  const float* wsq = (const float*)d_in[1];
  const float* bsq = (const float*)d_in[2];
  const float* we1 = (const float*)d_in[3];
  const float* be1 = (const float*)d_in[4];
  const float* we3 = (const float*)d_in[5];
  const float* be3 = (const float*)d_in[6];
  float* out = (float*)d_out;
  float* ws  = (float*)d_ws;
  ushort* hq = (ushort*)((char*)d_ws + HQ_BYTES_OFF);

  hipLaunchKernelGGL(prep_kernel, dim3(64), dim3(256), 0, stream,
                     wsq, bsq, we1, be1, we3, be3, ws);
  hipMemsetAsync(hq, 0, (size_t)32*PHW*64, stream);   // zero pad rows/cols
  hipLaunchKernelGGL(squeeze_kernel, dim3(NPIX/64), dim3(256), 0, stream, x, ws, hq);
  hipLaunchKernelGGL(expand_kernel, dim3(28, 32), dim3(256), 0, stream, hq, ws, out);
}

// Round 15
// 43.287 us; speedup vs baseline: 1.3842x; 1.3842x over previous
//
#include <hip/hip_runtime.h>
#include <stdint.h>

typedef __bf16 bf16x8 __attribute__((ext_vector_type(8)));
typedef float  f32x4  __attribute__((ext_vector_type(4)));

#define HW   3136
#define WID  56
#define CIN  128
#define SQ   32

// workspace layout (bytes unless noted)
#define OFF_BSQ 0              // f32[32]  (float offset 0)
#define OFF_BE  32             // f32[256] (float offset 32) e1 then e3
#define WSQF_BYTES_OFF 1152    // bf16 [2mf*4kc][64 lane][8] = 8192 B
#define WE1F_BYTES_OFF 9344    // bf16 [8 mf][64 lane][8] = 8192 B
#define WE3F_BYTES_OFF 17536   // bf16 [8 mf][9 tap][64 lane][8] = 73728 B

__device__ __forceinline__ float quant_w8(float x){
  float xc = fminf(fmaxf(x,-1.f),1.f);
  return fminf(rintf(xc*128.f)*0.0078125f, 0.9921875f);
}
// weight as integer n = 128*wq in [-128,127], stored as exact bf16
__device__ __forceinline__ ushort wq_int_bf16(float x){
  float xc = fminf(fmaxf(x,-1.f),1.f);
  float n = fminf(rintf(xc*128.f), 127.f);
  return (ushort)(__float_as_uint(n)>>16);
}
__device__ __forceinline__ uint pack2f(float a, float b){
  return (__float_as_uint(a)>>16) | (__float_as_uint(b)&0xffff0000u);
}

__global__ void prep_kernel(const float* __restrict__ wsq, const float* __restrict__ bsq,
                            const float* __restrict__ we1, const float* __restrict__ be1,
                            const float* __restrict__ we3, const float* __restrict__ be3,
                            float* __restrict__ ws){
  int tid = blockIdx.x*blockDim.x+threadIdx.x;
  int nth = gridDim.x*blockDim.x;
  ushort* wsqf = (ushort*)((char*)ws + WSQF_BYTES_OFF);
  ushort* we1f = (ushort*)((char*)ws + WE1F_BYTES_OFF);
  ushort* we3f = (ushort*)((char*)ws + WE3F_BYTES_OFF);
  for (int i=tid;i<SQ;i+=nth) ws[OFF_BSQ+i]=quant_w8(bsq[i]);
  for (int i=tid;i<256;i+=nth) ws[OFF_BE+i] = (i<128)? quant_w8(be1[i]) : quant_w8(be3[i-128]);
  // squeeze W frags: A[co=mf*16+(l&15)][ci=kc*32+(l>>4)*8+j], src wsq (32,128)
  for (int i=tid;i<4096;i+=nth){
    int mfkc=i>>9, l=(i>>3)&63, j=i&7;
    int mf=mfkc>>2, kc=mfkc&3;
    int co=mf*16+(l&15), ci=kc*32+(l>>4)*8+j;
    wsqf[i] = wq_int_bf16(wsq[co*CIN+ci]);
  }
  // e1 frags: [co=mf*16+(l&15)][k=ci=(l>>4)*8+j], src we1 (128,32)
  for (int i=tid;i<4096;i+=nth){
    int mf=i>>9, l=(i>>3)&63, j=i&7;
    int co=mf*16+(l&15), ci=(l>>4)*8+j;
    we1f[i] = wq_int_bf16(we1[co*SQ+ci]);
  }
  // e3 frags per tap, src we3 (128,32,3,3)
  for (int i=tid;i<36864;i+=nth){
    int mf=i/4608, r=i-mf*4608, t=r>>9, l=(r>>3)&63, j=r&7;
    int co=mf*16+(l&15), ci=(l>>4)*8+j;
    we3f[i] = wq_int_bf16(we3[(co*SQ+ci)*9+t]);
  }
}

// Fused fire: squeeze (MFMA) -> LDS h-tile -> expand e1+e3 (MFMA).
// Tile: 8 output rows of one image. Grid 224 flat, bijective per-XCD image grouping:
// XCD k (= wg%8) owns images 4k..4k+3, bry-adjacent tiles consecutive -> halo rows
// are same-XCD L2 hits. 512 threads (8 waves).
__global__ __launch_bounds__(512, 2) void fire_kernel(const float* __restrict__ x,
    const float* __restrict__ ws, float* __restrict__ out){
  __shared__ uint4 lds4[2320];   // h tile [10 rows][58 cols] x 32ci bf16 (64B), 16B-chunk XOR swizzle
  int wg = blockIdx.x;
  int logical = (wg & 7)*28 + (wg >> 3);   // bijective: 224 = 8 XCDs x 28
  int n   = logical/7;           // 0..31
  int bry = logical - n*7;       // 0..6
  int tid = threadIdx.x, w = tid>>6, lane = tid&63;
  int colg = lane&15, kg = lane>>4;
  int R0 = bry*8;
  int vr0 = (R0==0) ? 0 : R0-1;
  int vr1 = (R0+8 > 55) ? 55 : R0+8;
  int limit = (vr1+1)*WID;                 // end pixel (exclusive) of valid h rows
  int nblk = ((vr1-vr0+1)*WID + 15)>>4;    // 16-px squeeze blocks
  int base_px = vr0*WID;

  uint4 z = make_uint4(0,0,0,0);
  for (int i=tid; i<2320; i+=512) lds4[i] = z;
  __syncthreads();

  // ---- phase 1: squeeze into LDS (verified integer-exact MFMA path) ----
  {
    const bf16x8* wsqf = (const bf16x8*)((const char*)ws + WSQF_BYTES_OFF);
    bf16x8 W[8];
    #pragma unroll
    for (int q=0;q<8;++q) W[q] = wsqf[q*64 + lane];
    float bias[2][4];
    #pragma unroll
    for (int mf=0;mf<2;++mf)
      #pragma unroll
      for (int r=0;r<4;++r) bias[mf][r] = ws[OFF_BSQ + mf*16 + kg*4 + r];

    for (int b=w; b<nblk; b+=8){
      int px = base_px + b*16 + colg;
      int pxc = (px < limit) ? px : (limit-1);
      const float* xp = x + (size_t)n*CIN*HW + pxc;
      float xv[32];
      #pragma unroll
      for (int kc=0;kc<4;++kc)
        #pragma unroll
        for (int j=0;j<8;++j)
          xv[kc*8+j] = xp[(size_t)(kc*32 + kg*8 + j)*HW];

      bf16x8 Bf[4];
      #pragma unroll
      for (int kc=0;kc<4;++kc){
        float m[8];
        #pragma unroll
        for (int j=0;j<8;++j){
          float v = fminf(fmaxf(xv[kc*8+j],-4.f),4.f);
          m[j] = fminf(rintf(v*32.f), 127.f);      // m = 32*xq, exact bf16
        }
        union { uint u[4]; bf16x8 v; } cv;
        #pragma unroll
        for (int q=0;q<4;++q) cv.u[q] = pack2f(m[q*2], m[q*2+1]);
        Bf[kc] = cv.v;
      }

      f32x4 acc0 = (f32x4){0.f,0.f,0.f,0.f};
      f32x4 acc1 = (f32x4){0.f,0.f,0.f,0.f};
      #pragma unroll
      for (int kc=0;kc<4;++kc){
        acc0 = __builtin_amdgcn_mfma_f32_16x16x32_bf16(W[kc],   Bf[kc], acc0, 0,0,0);
        acc1 = __builtin_amdgcn_mfma_f32_16x16x32_bf16(W[4+kc], Bf[kc], acc1, 0,0,0);
      }

      if (px < limit){
        int rr = px/WID, c = px - rr*WID;
        int ph = (rr - R0 + 1)*58 + c + 1;       // LDS pixel index
        #pragma unroll
        for (int mf=0;mf<2;++mf){
          f32x4 a = mf ? acc1 : acc0;
          float m[4];
          #pragma unroll
          for (int r=0;r<4;++r){
            float y = fmaf(a[r], 0.000244140625f, bias[mf][r]);
            y = fminf(fmaxf(y,-8.f),8.f);
            y = fminf(rintf(y*16.f)*0.0625f, 7.9375f);
            y = fmaxf(y,0.f);
            y = fminf(y,4.f);
            y = fminf(y,0.9998779296875f);
            m[r] = rintf(y*32.f);                // m32 in {0,2,...,32}, exact bf16
          }
          int chunk = mf*2 + (kg>>1);
          int idx = ph*4 + (chunk ^ ((ph>>1)&3));
          uint* dst = (uint*)&lds4[idx] + (kg&1)*2;
          dst[0] = pack2f(m[0], m[1]);
          dst[1] = pack2f(m[2], m[3]);
        }
      }
    }
  }
  __syncthreads();

  // ---- phase 2: fused expand e1+e3 (verified swapped-operand MFMA path) ----
  int wid = w&3, rpl = w>>2;                 // 4 m-groups x 2 row-pair halves
  const bf16x8* we1f = (const bf16x8*)((const char*)ws + WE1F_BYTES_OFF);
  const bf16x8* we3f = (const bf16x8*)((const char*)ws + WE3F_BYTES_OFF);
  const bf16x8* lbase = (const bf16x8*)lds4;

  #pragma unroll
  for (int s=0; s<2; ++s){
    int rp = rpl*2 + s;                      // row-pair 0..3 (output rows R0+2rp, +1)
    int baseh[7];
    #pragma unroll
    for (int nf=0;nf<7;++nf){
      int p = rp*112 + nf*16 + colg;
      int rr = p/WID, c = p - rr*WID;
      baseh[nf] = (rr+1)*58 + c + 1;
    }

    f32x4 acc[4][7];
    #pragma unroll
    for (int mi=0;mi<4;++mi)
      #pragma unroll
      for (int nf=0;nf<7;++nf)
        acc[mi][nf] = (f32x4){0.f,0.f,0.f,0.f};

    #pragma unroll
    for (int t=0;t<9;++t){
      int off = (t/3 - 1)*58 + (t%3 - 1);
      bf16x8 B[7];
      #pragma unroll
      for (int nf=0;nf<7;++nf){
        int ph = baseh[nf] + off;
        int idx = ph*4 + (kg ^ ((ph>>1)&3));
        B[nf] = lbase[idx];
      }
      bf16x8 A2 = we3f[(wid*9+t)*64 + lane];
      bf16x8 A3 = we3f[((wid+4)*9+t)*64 + lane];
      #pragma unroll
      for (int nf=0;nf<7;++nf){
        acc[2][nf] = __builtin_amdgcn_mfma_f32_16x16x32_bf16(B[nf], A2, acc[2][nf], 0,0,0);
        acc[3][nf] = __builtin_amdgcn_mfma_f32_16x16x32_bf16(B[nf], A3, acc[3][nf], 0,0,0);
      }
      if (t==4){
        bf16x8 A0 = we1f[wid*64 + lane];
        bf16x8 A1 = we1f[(wid+4)*64 + lane];
        #pragma unroll
        for (int nf=0;nf<7;++nf){
          acc[0][nf] = __builtin_amdgcn_mfma_f32_16x16x32_bf16(B[nf], A0, acc[0][nf], 0,0,0);
          acc[1][nf] = __builtin_amdgcn_mfma_f32_16x16x32_bf16(B[nf], A1, acc[1][nf], 0,0,0);
        }
      }
    }

    // epilogue: C col=cout(colg), row=pixel(kg*4+r) -> plain float4 stores
    #pragma unroll
    for (int mi=0;mi<4;++mi){
      int co = (wid+mi*4)*16 + colg;
      float bias = ws[OFF_BE + co];
      float* opb = out + (size_t)(n*256+co)*HW + R0*WID + rp*112 + kg*4;
      #pragma unroll
      for (int nf=0;nf<7;++nf){
        f32x4 a = acc[mi][nf];
        f32x4 yv;
        #pragma unroll
        for (int r=0;r<4;++r){
          float y = fmaf(a[r], 0.000244140625f, bias);
          y = fminf(fmaxf(y,-8.f),8.f);
          y = fminf(rintf(y*16.f)*0.0625f, 7.9375f);
          y = fmaxf(y,0.f);
          yv[r] = y;
        }
        *(f32x4*)(opb + nf*16) = yv;
      }
    }
  }
}

extern "C" void kernel_launch(void* const* d_in, const int* in_sizes, int n_in,
                              void* d_out, int out_size, void* d_ws, size_t ws_size,
                              hipStream_t stream){
  const float* x   = (const float*)d_in[0];
  const float* wsq = (const float*)d_in[1];
  const float* bsq = (const float*)d_in[2];
  const float* we1 = (const float*)d_in[3];
  const float* be1 = (const float*)d_in[4];
  const float* we3 = (const float*)d_in[5];
  const float* be3 = (const float*)d_in[6];
  float* out = (float*)d_out;
  float* ws  = (float*)d_ws;

  hipLaunchKernelGGL(prep_kernel, dim3(64), dim3(256), 0, stream,
                     wsq, bsq, we1, be1, we3, be3, ws);
  hipLaunchKernelGGL(fire_kernel, dim3(224), dim3(512), 0, stream, x, ws, out);
}